// Round 14
// baseline (380.153 us; speedup 1.0000x reference)
//
#include <hip/hip_runtime.h>
#include <hip/hip_bf16.h>

// out[bt,o] = b[o] + sum_{i,j} Xa[bt,i]*Xb[bt,j]*W[o, i*257+j], Xa=[1,X], Xb=[1,X_aux]
// Chunk c in [0,258):
//   c<256 : contrib = X[r,c] * sum_j Xb[r,j]*Bp[c][o][j]
//   c=256 : contrib =          sum_j Xb[r,j]*Bp[256][o][j]
//   c=257 : contrib =          sum_j X [r,j]*Bp[257][o][j]
// k=0 corner (W[o,0]) folded into reduce with bias.
//
// R14: B-operand direct from global (L2-resident Bp) to registers using
// PLAIN compiler-tracked loads (R13's inline-asm loads crashed: untracked
// async VGPR writes). Lead-1 double buffer fb[2][4]; compiler inserts exact
// vmcnt before the consuming MFMA. No Bs LDS, no K-loop barriers (waves
// free-run; 2 waves/SIMD TLP hides L2 latency). LDS = chunk-invariant As
// (64KB) + Ss scales (17KB) only.

#define DI 66049

typedef __attribute__((ext_vector_type(8))) short bf16x8;
typedef __attribute__((ext_vector_type(4))) float f32x4;
typedef __attribute__((ext_vector_type(4))) int i32x4;

__device__ __forceinline__ unsigned short f2b(float f) {
  union { __hip_bfloat16 h; unsigned short u; } cv;
  cv.h = __float2bfloat16(f);
  return cv.u;
}

__device__ __forceinline__ bf16x8 pack8(f32x4 lo, f32x4 hi) {
  bf16x8 r;
  r[0] = (short)f2b(lo[0]); r[1] = (short)f2b(lo[1]);
  r[2] = (short)f2b(lo[2]); r[3] = (short)f2b(lo[3]);
  r[4] = (short)f2b(hi[0]); r[5] = (short)f2b(hi[1]);
  r[6] = (short)f2b(hi[2]); r[7] = (short)f2b(hi[3]);
  return r;
}

// ---- prep: gather W (f32) into bf16 Bp[c][o][j] (linear), c in [0,258)
__global__ void prep_w(const float* __restrict__ W, unsigned short* __restrict__ Bp) {
  const int c = blockIdx.x;
  const int o = (blockIdx.y << 2) + (threadIdx.x >> 6);
  const int j = (threadIdx.x & 63) << 2;
  const float* wrow = W + (size_t)o * DI;
  float v0, v1, v2, v3;
  if (c < 256) {
    const int bse = (c + 1) * 257 + 1 + j;
    v0 = wrow[bse]; v1 = wrow[bse + 1]; v2 = wrow[bse + 2]; v3 = wrow[bse + 3];
  } else if (c == 256) {
    const int bse = 1 + j;
    v0 = wrow[bse]; v1 = wrow[bse + 1]; v2 = wrow[bse + 2]; v3 = wrow[bse + 3];
  } else {
    v0 = wrow[(j + 1) * 257]; v1 = wrow[(j + 2) * 257];
    v2 = wrow[(j + 3) * 257]; v3 = wrow[(j + 4) * 257];
  }
  unsigned short* dst = Bp + (((size_t)c << 8) + o) * 256 + j;
  const unsigned int lo = (unsigned int)f2b(v0) | ((unsigned int)f2b(v1) << 16);
  const unsigned int hi = (unsigned int)f2b(v2) | ((unsigned int)f2b(v3) << 16);
  *(uint2*)dst = make_uint2(lo, hi);
}

// ---- prep: Xt[c][bt] = X[bt][c]  (f32 transpose for coalesced scale loads)
__global__ void prep_xt(const float* __restrict__ X, float* __restrict__ Xt) {
  __shared__ float t[32][33];
  const int tx = threadIdx.x, ty = threadIdx.y;
  const int bt0 = blockIdx.x << 5, c0 = blockIdx.y << 5;
#pragma unroll
  for (int k = 0; k < 4; ++k) {
    const int row = (ty << 2) + k;
    t[row][tx] = X[(size_t)(bt0 + row) * 256 + c0 + tx];
  }
  __syncthreads();
#pragma unroll
  for (int k = 0; k < 4; ++k) {
    const int row = (ty << 2) + k;
    Xt[(size_t)(c0 + row) * 4096 + bt0 + tx] = t[tx][row];
  }
}

// pack As[128][256] bf16 from SRC rows [bt0,bt0+128), 16-slot XOR swizzle
#define PACK_AS(SRC)                                                           \
  {                                                                            \
    const int _row = tid >> 2, _q = tid & 3;                                   \
    const float* _rp = (SRC) + (size_t)(bt0 + _row) * 256 + (_q << 6);         \
    const int _sx = _row & 15;                                                 \
    _Pragma("unroll") for (int _w = 0; _w < 8; ++_w) {                         \
      f32x4 _lo = *(const f32x4*)(_rp + (_w << 3));                            \
      f32x4 _hi = *(const f32x4*)(_rp + (_w << 3) + 4);                        \
      const int _slot = (_q << 3) + _w;                                        \
      *(bf16x8*)(&As[_row * 256 + ((_slot ^ _sx) << 3)]) = pack8(_lo, _hi);    \
    }                                                                          \
  }

// read A fragment set S for k-window W (chunk-invariant)
#define READ_A(W, S)                                                           \
  {                                                                            \
    _Pragma("unroll") for (int _rg = 0; _rg < 4; ++_rg) {                      \
      const int _ra = wr + (_rg << 4) + l15;                                   \
      fa[S][_rg] = *(const bf16x8*)(&As[_ra * 256 +                            \
                                        (((((W) << 2) + lg) ^ (_ra & 15))      \
                                         << 3)]);                              \
    }                                                                          \
  }

// issue 4 B-fragment loads (compiler-tracked) for unit base UB into fb[S]
#define ISSUE_B(S, UB)                                                         \
  {                                                                            \
    _Pragma("unroll") for (int _fn = 0; _fn < 4; ++_fn)                        \
        fb[S][_fn] = *(const i32x4*)((UB) + boff[_fn]);                        \
  }

// 16 MFMA on set S into t
#define MFMA_SET(S)                                                            \
  {                                                                            \
    __builtin_amdgcn_s_setprio(1);                                             \
    _Pragma("unroll") for (int _rg = 0; _rg < 4; ++_rg)                        \
      _Pragma("unroll") for (int _fn = 0; _fn < 4; ++_fn)                      \
        t[_rg][_fn] = __builtin_amdgcn_mfma_f32_16x16x32_bf16(                 \
            fa[S][_rg], __builtin_bit_cast(bf16x8, fb[S][_fn]),                \
            t[_rg][_fn], 0, 0, 0);                                             \
    __builtin_amdgcn_s_setprio(0);                                             \
  }

__global__ __launch_bounds__(512, 1) void gemm_r14(
    const float* __restrict__ X, const float* __restrict__ Xb,
    const float* __restrict__ Xt, const unsigned short* __restrict__ Bp,
    float* __restrict__ P) {
  __shared__ __align__(16) unsigned short As[128 * 256];  // 64 KB static A
  __shared__ __align__(16) float Ss[33 * 128];            // 16.9 KB scales

  const int tid = threadIdx.x;
  const int rid = blockIdx.x;

  int bx, c0, nCh, Pslice;
  const float* Asrc;
  if (rid < 256) {                 // main slices, XCD-pinned by rid&7
    const int slice = rid & 7;
    bx = rid >> 3;
    c0 = slice << 5;
    nCh = (slice == 7) ? 33 : 32;  // slice 7 covers c in [224,257)
    Asrc = Xb;
    Pslice = slice;
  } else {                         // c = 257 blocks (A = X)
    bx = rid - 256;
    c0 = 257;
    nCh = 1;
    Asrc = X;
    Pslice = 8;
  }
  const int bt0 = bx << 7;
  const int nU = nCh << 3;

  const int wid = tid >> 6, lane = tid & 63;
  const int wm = wid >> 2, wn = wid & 3;  // 2 (bt) x 4 (o) waves
  const int wr = wm << 6;
  const int l15 = lane & 15, lg = lane >> 4;

  // B-frag offsets (elements): row (o-col) = wn*64 + fn*16 + l15, k-slot lg
  unsigned boff[4];
#pragma unroll
  for (int fn = 0; fn < 4; ++fn)
    boff[fn] = (unsigned)(((wn << 6) + (fn << 4) + l15) * 256 + (lg << 3));

  PACK_AS(Asrc);
  // scale table: Ss[ci*128 + r] = X[bt0+r, c0+ci] (1.0 for c >= 256)
  for (int i = tid; i < (nCh << 7); i += 512) {
    const int ci2 = i >> 7, r = i & 127;
    const int c = c0 + ci2;
    Ss[i] = (c < 256) ? Xt[(size_t)c * 4096 + bt0 + r] : 1.0f;
  }
  __syncthreads();  // As/Ss visible

  i32x4 fb[2][4];
  bf16x8 fa[2][4];

  // prologue: unit 0 into set 0
  ISSUE_B(0, Bp + ((size_t)c0 << 16));
  READ_A(0, 0);

  f32x4 acc[4][4] = {};

  for (int ci = 0; ci < nCh; ++ci) {
    f32x4 t[4][4] = {};
#pragma unroll
    for (int uh = 0; uh < 8; ++uh) {
      const int S = uh & 1, S2 = S ^ 1;
      const int u = (ci << 3) + uh;
      int v = u + 1;
      if (v > nU - 1) v = nU - 1;  // clamp: tail prefetch harmless (unused)
      const unsigned short* ub =
          Bp + ((size_t)(c0 + (v >> 3)) << 16) + ((v & 7) << 5);
      ISSUE_B(S2, ub);             // lead-1: B(u+1), compiler-tracked
      READ_A((uh + 1) & 7, S2);    // A window (chunk-invariant)
      MFMA_SET(S);                 // compiler waits only on set-S loads
    }
    // fold chunk: acc += s4 * t
    f32x4 s4[4];
#pragma unroll
    for (int rg = 0; rg < 4; ++rg)
      s4[rg] = *(const f32x4*)(&Ss[(ci << 7) + wr + (rg << 4) + (lg << 2)]);
#pragma unroll
    for (int rg = 0; rg < 4; ++rg)
#pragma unroll
      for (int fn = 0; fn < 4; ++fn) acc[rg][fn] += s4[rg] * t[rg][fn];
  }

  // ---- epilogue: C layout col = lane&15, row = (lane>>4)*4 + reg
  float* pp = P + ((size_t)Pslice << 20);
#pragma unroll
  for (int rg = 0; rg < 4; ++rg) {
    const int row = bt0 + wr + (rg << 4) + (lg << 2);
#pragma unroll
    for (int fn = 0; fn < 4; ++fn) {
      const int col = (wn << 6) + (fn << 4) + l15;
#pragma unroll
      for (int e = 0; e < 4; ++e)
        pp[(size_t)(row + e) * 256 + col] = acc[rg][fn][e];
    }
  }
}

// ---- reduce: sum 9 partial slices + bias + W[o,0]
__global__ void reduce_k(const float* __restrict__ P, const float* __restrict__ W,
                         const float* __restrict__ b, float* __restrict__ out,
                         int nsl) {
  const int idx = blockIdx.x * 256 + threadIdx.x;
  const int o = idx & 255;
  float v = b[o] + W[(size_t)o * DI];
  for (int s = 0; s < nsl; ++s) v += P[idx + (size_t)s * 1048576];
  out[idx] = v;
}

// ================= fallback path (tiny ws): R2 proven kernels ================
__global__ void init_k(const float* __restrict__ W, const float* __restrict__ b,
                       float* __restrict__ out) {
  const int idx = blockIdx.x * 256 + threadIdx.x;
  const int o = idx & 255;
  out[idx] = b[o] + W[(size_t)o * DI];
}

__global__ __launch_bounds__(256, 4) void gemm_fb(
    const float* __restrict__ X, const float* __restrict__ Xa,
    const float* __restrict__ W, float* __restrict__ Out) {
  __shared__ __align__(16) unsigned short Asf[128 * 64];
  __shared__ __align__(16) unsigned short Bsf[128 * 64];
  const int tid = threadIdx.x;
  const int bx = blockIdx.x, by = blockIdx.y, bz = blockIdx.z;
  const int S = gridDim.z;
  const int bt0 = bx << 7, o0 = by << 7;
  const int q = 258 / S, r = 258 % S;
  const int c0 = bz * q + (bz < r ? bz : r);
  const int ccnt = q + (bz < r ? 1 : 0);
  const int nK = ccnt << 2;
  const int wid = tid >> 6, lane = tid & 63;
  const int wr = (wid >> 1) << 6, wc = (wid & 1) << 6;
  const int ar = tid >> 1;
  const int ah = (tid & 1) << 5;
  const float* xrow = X + (size_t)(bt0 + ar) * 256;
  const float* varow = Xa + (size_t)(bt0 + ar) * 256;
  f32x4 acc[4][4] = {};
  for (int kt = 0; kt < nK; ++kt) {
    const int c = c0 + (kt >> 2);
    const int j0 = (kt & 3) << 6;
    __syncthreads();
    {
      const float* vs = (c == 257) ? xrow : varow;
      float s = 1.0f;
      if (c < 256) s = xrow[c];
      const f32x4* vp = (const f32x4*)(vs + j0 + ah);
      f32x4 v[8];
#pragma unroll
      for (int qq = 0; qq < 8; ++qq) v[qq] = vp[qq];
      unsigned short* aw = Asf + ar * 64;
      const int sl0 = ah >> 3, sx = ar & 7;
#pragma unroll
      for (int w = 0; w < 4; ++w) {
        bf16x8 pk;
#pragma unroll
        for (int e = 0; e < 8; ++e)
          pk[e] = (short)f2b(s * v[w * 2 + (e >> 2)][e & 3]);
        *(bf16x8*)(aw + (((sl0 + w) ^ sx) << 3)) = pk;
      }
    }
    {
      const int orow = tid >> 1;
      const int jh = (tid & 1) << 5;
      const float* wrow = W + (size_t)(o0 + orow) * DI;
      float tmp[32];
      if (c < 256) {
        const int bse = (c + 1) * 257 + 1 + j0 + jh;
#pragma unroll
        for (int i = 0; i < 32; ++i) tmp[i] = wrow[bse + i];
      } else if (c == 256) {
        const int bse = 1 + j0 + jh;
#pragma unroll
        for (int i = 0; i < 32; ++i) tmp[i] = wrow[bse + i];
      } else {
#pragma unroll
        for (int i = 0; i < 32; ++i) tmp[i] = wrow[(j0 + jh + i + 1) * 257];
      }
      unsigned short* bw = Bsf + orow * 64;
      const int sl0 = jh >> 3, sx = orow & 7;
#pragma unroll
      for (int w = 0; w < 4; ++w) {
        bf16x8 pk;
#pragma unroll
        for (int e = 0; e < 8; ++e) pk[e] = (short)f2b(tmp[w * 8 + e]);
        *(bf16x8*)(bw + (((sl0 + w) ^ sx) << 3)) = pk;
      }
    }
    __syncthreads();
#pragma unroll
    for (int kk = 0; kk < 2; ++kk) {
      const int kslot = (kk << 2) + (lane >> 4);
      bf16x8 af[4], bfr2[4];
#pragma unroll
      for (int fm = 0; fm < 4; ++fm) {
        const int row = wr + (fm << 4) + (lane & 15);
        af[fm] = *(const bf16x8*)(Asf + row * 64 + ((kslot ^ (row & 7)) << 3));
      }
#pragma unroll
      for (int fn = 0; fn < 4; ++fn) {
        const int row = wc + (fn << 4) + (lane & 15);
        bfr2[fn] = *(const bf16x8*)(Bsf + row * 64 + ((kslot ^ (row & 7)) << 3));
      }
#pragma unroll
      for (int fm = 0; fm < 4; ++fm)
#pragma unroll
        for (int fn = 0; fn < 4; ++fn)
          acc[fm][fn] = __builtin_amdgcn_mfma_f32_16x16x32_bf16(
              af[fm], bfr2[fn], acc[fm][fn], 0, 0, 0);
    }
  }
  const int r0 = (lane >> 4) << 2;
  const int cl = lane & 15;
#pragma unroll
  for (int fm = 0; fm < 4; ++fm) {
    const int row = bt0 + wr + (fm << 4) + r0;
#pragma unroll
    for (int fn = 0; fn < 4; ++fn) {
      const int col = o0 + wc + (fn << 4) + cl;
#pragma unroll
      for (int rr = 0; rr < 4; ++rr)
        atomicAdd(Out + (size_t)(row + rr) * 256 + col, acc[fm][fn][rr]);
    }
  }
}

extern "C" void kernel_launch(void* const* d_in, const int* in_sizes, int n_in,
                              void* d_out, int out_size, void* d_ws, size_t ws_size,
                              hipStream_t stream) {
  const float* X  = (const float*)d_in[0];
  const float* Xa = (const float*)d_in[1];
  const float* W  = (const float*)d_in[2];
  const float* b  = (const float*)d_in[3];
  float* out = (float*)d_out;

  const size_t WBF_SZ = (size_t)258 * 256 * 256 * 2;  // 33,816,576 B
  const size_t XT_SZ  = (size_t)256 * 4096 * 4;       //  4,194,304 B
  const size_t PART1  = (size_t)4096 * 256 * 4;       //  4 MiB per slice

  if (ws_size >= WBF_SZ + XT_SZ + 9 * PART1) {
    unsigned short* Bp = (unsigned short*)d_ws;
    float* Xt = (float*)((char*)d_ws + WBF_SZ);
    float* P  = (float*)((char*)d_ws + WBF_SZ + XT_SZ);
    prep_w<<<dim3(258, 64), 256, 0, stream>>>(W, Bp);
    prep_xt<<<dim3(128, 8), dim3(32, 8), 0, stream>>>(X, Xt);
    gemm_r14<<<dim3(288), 512, 0, stream>>>(X, Xa, Xt, Bp, P);
    reduce_k<<<4096, 256, 0, stream>>>(P, W, b, out, 9);
  } else {
    init_k<<<4096, 256, 0, stream>>>(W, b, out);
    gemm_fb<<<dim3(32, 2, 4), 256, 0, stream>>>(X, Xa, W, out);
  }
}

// Round 15
// 171.893 us; speedup vs baseline: 2.2116x; 2.2116x over previous
//
#include <hip/hip_runtime.h>
#include <hip/hip_bf16.h>

// out[bt,o] = b[o] + sum_{i,j} Xa[bt,i]*Xb[bt,j]*W[o, i*257+j], Xa=[1,X], Xb=[1,X_aux]
// Chunk c in [0,258):
//   c<256 : contrib = X[r,c] * sum_j Xb[r,j]*Bp[c][o][j]
//   c=256 : contrib =          sum_j Xb[r,j]*Bp[256][o][j]
//   c=257 : contrib =          sum_j X [r,j]*Bp[257][o][j]
// k=0 corner (W[o,0]) folded into reduce with bias.
//
// R15 = R10 + asm-owned DS reads. Diagnosis: R10's LDS (571cy) and MFMA
// (621cy) pipes measured SERIAL (1336cy/unit) -> compiler emits conservative
// lgkmcnt(0) before MFMA, waiting for the just-issued next-unit reads.
// Fix (rule-18 pattern): fragment reads via inline-asm ds_read_b128 (compiler
// inserts no waits for asm-defined regs) + explicit counted lgkmcnt(8|12) +
// sched_barrier(0) before the MFMA cluster. DS queue audit: at MFMA(u) the
// only outstanding DS = 8 reads(u+1) (+4 Ss reads at uh==7, issued first);
// fold waits lgkmcnt(8) for Ss.

#define DI 66049

typedef __attribute__((ext_vector_type(8))) short bf16x8;
typedef __attribute__((ext_vector_type(4))) float f32x4;

__device__ __forceinline__ unsigned short f2b(float f) {
  union { __hip_bfloat16 h; unsigned short u; } cv;
  cv.h = __float2bfloat16(f);
  return cv.u;
}

__device__ __forceinline__ bf16x8 pack8(f32x4 lo, f32x4 hi) {
  bf16x8 r;
  r[0] = (short)f2b(lo[0]); r[1] = (short)f2b(lo[1]);
  r[2] = (short)f2b(lo[2]); r[3] = (short)f2b(lo[3]);
  r[4] = (short)f2b(hi[0]); r[5] = (short)f2b(hi[1]);
  r[6] = (short)f2b(hi[2]); r[7] = (short)f2b(hi[3]);
  return r;
}

__device__ __forceinline__ void gload16(const void* g, void* l) {
  __builtin_amdgcn_global_load_lds(
      (const __attribute__((address_space(1))) unsigned int*)g,
      (__attribute__((address_space(3))) unsigned int*)l, 16, 0, 0);
}

// ---- prep: gather W (f32) into bf16 Bp[c][o][j] (linear), c in [0,258)
__global__ void prep_w(const float* __restrict__ W, unsigned short* __restrict__ Bp) {
  const int c = blockIdx.x;
  const int o = (blockIdx.y << 2) + (threadIdx.x >> 6);
  const int j = (threadIdx.x & 63) << 2;
  const float* wrow = W + (size_t)o * DI;
  float v0, v1, v2, v3;
  if (c < 256) {
    const int bse = (c + 1) * 257 + 1 + j;
    v0 = wrow[bse]; v1 = wrow[bse + 1]; v2 = wrow[bse + 2]; v3 = wrow[bse + 3];
  } else if (c == 256) {
    const int bse = 1 + j;
    v0 = wrow[bse]; v1 = wrow[bse + 1]; v2 = wrow[bse + 2]; v3 = wrow[bse + 3];
  } else {
    v0 = wrow[(j + 1) * 257]; v1 = wrow[(j + 2) * 257];
    v2 = wrow[(j + 3) * 257]; v3 = wrow[(j + 4) * 257];
  }
  unsigned short* dst = Bp + (((size_t)c << 8) + o) * 256 + j;
  const unsigned int lo = (unsigned int)f2b(v0) | ((unsigned int)f2b(v1) << 16);
  const unsigned int hi = (unsigned int)f2b(v2) | ((unsigned int)f2b(v3) << 16);
  *(uint2*)dst = make_uint2(lo, hi);
}

// ---- prep: Xt[c][bt] = X[bt][c]  (f32 transpose for coalesced scale loads)
__global__ void prep_xt(const float* __restrict__ X, float* __restrict__ Xt) {
  __shared__ float t[32][33];
  const int tx = threadIdx.x, ty = threadIdx.y;
  const int bt0 = blockIdx.x << 5, c0 = blockIdx.y << 5;
#pragma unroll
  for (int k = 0; k < 4; ++k) {
    const int row = (ty << 2) + k;
    t[row][tx] = X[(size_t)(bt0 + row) * 256 + c0 + tx];
  }
  __syncthreads();
#pragma unroll
  for (int k = 0; k < 4; ++k) {
    const int row = (ty << 2) + k;
    Xt[(size_t)(c0 + row) * 4096 + bt0 + tx] = t[tx][row];
  }
}

// pack As[128][256] bf16 from SRC rows [bt0,bt0+128), 16-slot XOR swizzle
#define PACK_AS(SRC)                                                           \
  {                                                                            \
    const int _row = tid >> 2, _q = tid & 3;                                   \
    const float* _rp = (SRC) + (size_t)(bt0 + _row) * 256 + (_q << 6);         \
    const int _sx = _row & 15;                                                 \
    _Pragma("unroll") for (int _w = 0; _w < 8; ++_w) {                         \
      f32x4 _lo = *(const f32x4*)(_rp + (_w << 3));                            \
      f32x4 _hi = *(const f32x4*)(_rp + (_w << 3) + 4);                        \
      const int _slot = (_q << 3) + _w;                                        \
      *(bf16x8*)(&As[_row * 256 + ((_slot ^ _sx) << 3)]) = pack8(_lo, _hi);    \
    }                                                                          \
  }

// stage one K=32 unit V into Bs[SLOT]: 2 x gload16/thread, 32-bit offsets
#define STAGE_U(V, SLOT)                                                       \
  {                                                                            \
    const unsigned short* _bse =                                               \
        Bp + ((size_t)(c0 + ((V) >> 3)) << 16) + (((V) & 7) << 5);             \
    gload16(_bse + stg_off0, &Bs[SLOT][(size_t)tid << 3]);                     \
    gload16(_bse + stg_off1, &Bs[SLOT][(size_t)(512 + tid) << 3]);             \
  }

// asm ds_read_b128 (compiler-untracked; WE own the lgkm counts)
#define DSR(DST, ADDR)                                                         \
  asm volatile("ds_read_b128 %0, %1" : "=v"(DST) : "v"(ADDR));

// issue 8 asm fragment reads for unit U into set S (A then B)
#define READ_ASM(U, S)                                                         \
  {                                                                            \
    const unsigned _w4 = ((unsigned)((U) & 7)) << 2;                           \
    _Pragma("unroll") for (int _rg = 0; _rg < 4; ++_rg) {                      \
      const unsigned _ad =                                                     \
          aRow[_rg] + (((_w4 + (unsigned)lg) ^ aXor[_rg]) << 4);               \
      DSR(fa[S][_rg], _ad);                                                    \
    }                                                                          \
    const unsigned _sb = bsBase + (((unsigned)((U) & 3)) << 14);               \
    _Pragma("unroll") for (int _fn = 0; _fn < 4; ++_fn) {                      \
      DSR(fb[S][_fn], _sb + bOff[_fn]);                                        \
    }                                                                          \
  }

// one unit: STAGE(u+3) -> vmcnt(4) -> barrier -> asm READ(u+1) [+Ss at uh7,
// issued FIRST] -> lgkmcnt(8|12) -> sched_barrier -> 16 MFMA(set uh&1)
#define UNIT(UH)                                                               \
  {                                                                            \
    const int _u = (ci << 3) + (UH);                                           \
    int _v = _u + 3;                                                           \
    if (_v > nU - 1) _v = nU - 1;                                              \
    STAGE_U(_v, (_u + 3) & 3);                                                 \
    asm volatile("s_waitcnt vmcnt(4)" ::: "memory");                           \
    __builtin_amdgcn_s_barrier();                                              \
    __builtin_amdgcn_sched_barrier(0);                                         \
    if ((UH) == 7) {                                                           \
      _Pragma("unroll") for (int _rg = 0; _rg < 4; ++_rg) {                    \
        DSR(s4[_rg], ssBase + ((unsigned)ci << 9) + sOff[_rg]);                \
      }                                                                        \
    }                                                                          \
    {                                                                          \
      int _un = _u + 1;                                                        \
      if (_un > nU - 1) _un = nU - 1;                                          \
      READ_ASM(_un, ((UH) + 1) & 1);                                           \
    }                                                                          \
    if ((UH) == 7) {                                                           \
      asm volatile("s_waitcnt lgkmcnt(12)" ::: "memory");                      \
    } else {                                                                   \
      asm volatile("s_waitcnt lgkmcnt(8)" ::: "memory");                       \
    }                                                                          \
    __builtin_amdgcn_sched_barrier(0);                                         \
    __builtin_amdgcn_s_setprio(1);                                             \
    _Pragma("unroll") for (int _rg = 0; _rg < 4; ++_rg)                        \
      _Pragma("unroll") for (int _fn = 0; _fn < 4; ++_fn)                      \
        t[_rg][_fn] = __builtin_amdgcn_mfma_f32_16x16x32_bf16(                 \
            fa[(UH) & 1][_rg], fb[(UH) & 1][_fn], t[_rg][_fn], 0, 0, 0);       \
    __builtin_amdgcn_s_setprio(0);                                             \
  }

__global__ __launch_bounds__(512, 1) void gemm_r15(
    const float* __restrict__ X, const float* __restrict__ Xb,
    const float* __restrict__ Xt, const unsigned short* __restrict__ Bp,
    float* __restrict__ P) {
  __shared__ __align__(16) unsigned short As[128 * 256];   // 64 KB static A
  __shared__ __align__(16) unsigned short Bs[4][256 * 32]; // 4 x 16 KB ring
  __shared__ __align__(16) float Ss[33 * 128];             // 16.9 KB scales

  const int tid = threadIdx.x;
  const int rid = blockIdx.x;

  int bx, c0, nCh, Pslice;
  const float* Asrc;
  if (rid < 256) {                 // main slices, XCD-pinned by rid&7
    const int slice = rid & 7;
    bx = rid >> 3;
    c0 = slice << 5;
    nCh = (slice == 7) ? 33 : 32;  // slice 7 covers c in [224,257)
    Asrc = Xb;
    Pslice = slice;
  } else {                         // c = 257 blocks (A = X)
    bx = rid - 256;
    c0 = 257;
    nCh = 1;
    Asrc = X;
    Pslice = 8;
  }
  const int bt0 = bx << 7;
  const int nU = nCh << 3;

  const int wid = tid >> 6, lane = tid & 63;
  const int wm = wid >> 2, wn = wid & 3;  // 2 (bt) x 4 (o) waves
  const int wr = wm << 6;
  const int l15 = lane & 15, lg = lane >> 4;

  // LDS byte-offset bases (AS(3) 32-bit addresses for asm ds_read)
  const unsigned asBase =
      (unsigned)(uintptr_t)(__attribute__((address_space(3))) unsigned short*)As;
  const unsigned bsBase =
      (unsigned)(uintptr_t)(__attribute__((address_space(3))) unsigned short*)&Bs[0][0];
  const unsigned ssBase =
      (unsigned)(uintptr_t)(__attribute__((address_space(3))) float*)Ss;

  // per-thread fragment address components
  unsigned aRow[4], aXor[4], bOff[4], sOff[4];
#pragma unroll
  for (int rg = 0; rg < 4; ++rg) {
    const int ra = wr + (rg << 4) + l15;
    aRow[rg] = asBase + (unsigned)ra * 512;
    aXor[rg] = (unsigned)(ra & 15);
    const int rb = (wn << 6) + (rg << 4) + l15;
    bOff[rg] = (unsigned)(rb * 64 + (((unsigned)lg ^ ((rb >> 1) & 3)) << 4));
    sOff[rg] = (unsigned)((wr + (rg << 4) + (lg << 2)) << 2);
  }

  // per-thread STAGE source offsets (pre-swizzled col group), 32-bit
  const int idx0 = tid, idx1 = 512 + tid;
  const int row0 = idx0 >> 2, row1 = idx1 >> 2;
  const unsigned stg_off0 =
      (unsigned)(row0 * 256 + (((idx0 & 3) ^ ((row0 >> 1) & 3)) << 3));
  const unsigned stg_off1 =
      (unsigned)(row1 * 256 + (((idx1 & 3) ^ ((row1 >> 1) & 3)) << 3));

  PACK_AS(Asrc);
  // scale table: Ss[ci*128 + r] = X[bt0+r, c0+ci] (1.0 for c >= 256)
  for (int i = tid; i < (nCh << 7); i += 512) {
    const int ci2 = i >> 7, r = i & 127;
    const int c = c0 + ci2;
    Ss[i] = (c < 256) ? Xt[(size_t)c * 4096 + bt0 + r] : 1.0f;
  }
  STAGE_U(0, 0);
  STAGE_U(1, 1);
  STAGE_U(2, 2);
  __syncthreads();  // As/Ss visible; stages 0-2 complete; DS queue empty

  bf16x8 fa[2][4], fb[2][4];
  f32x4 s4[4];

  READ_ASM(0, 0);  // prologue: unit 0 -> set 0 (queue = 8)

  f32x4 acc[4][4] = {};

  for (int ci = 0; ci < nCh; ++ci) {
    f32x4 t[4][4] = {};
    UNIT(0);
    UNIT(1);
    UNIT(2);
    UNIT(3);
    UNIT(4);
    UNIT(5);
    UNIT(6);
    UNIT(7);
    // fold: s4 (issued before UNIT(7)'s 8 frag reads) -> lgkmcnt(8)
    asm volatile("s_waitcnt lgkmcnt(8)" ::: "memory");
    __builtin_amdgcn_sched_barrier(0);
#pragma unroll
    for (int rg = 0; rg < 4; ++rg)
#pragma unroll
      for (int fn = 0; fn < 4; ++fn) acc[rg][fn] += s4[rg] * t[rg][fn];
  }

  // ---- epilogue: C layout col = lane&15, row = (lane>>4)*4 + reg
  float* pp = P + ((size_t)Pslice << 20);
#pragma unroll
  for (int rg = 0; rg < 4; ++rg) {
    const int row = bt0 + wr + (rg << 4) + (lg << 2);
#pragma unroll
    for (int fn = 0; fn < 4; ++fn) {
      const int col = (wn << 6) + (fn << 4) + l15;
#pragma unroll
      for (int e = 0; e < 4; ++e)
        pp[(size_t)(row + e) * 256 + col] = acc[rg][fn][e];
    }
  }
}

// ---- reduce: sum 9 partial slices + bias + W[o,0]
__global__ void reduce_k(const float* __restrict__ P, const float* __restrict__ W,
                         const float* __restrict__ b, float* __restrict__ out,
                         int nsl) {
  const int idx = blockIdx.x * 256 + threadIdx.x;
  const int o = idx & 255;
  float v = b[o] + W[(size_t)o * DI];
  for (int s = 0; s < nsl; ++s) v += P[idx + (size_t)s * 1048576];
  out[idx] = v;
}

// ================= fallback path (tiny ws): R2 proven kernels ================
__global__ void init_k(const float* __restrict__ W, const float* __restrict__ b,
                       float* __restrict__ out) {
  const int idx = blockIdx.x * 256 + threadIdx.x;
  const int o = idx & 255;
  out[idx] = b[o] + W[(size_t)o * DI];
}

__global__ __launch_bounds__(256, 4) void gemm_fb(
    const float* __restrict__ X, const float* __restrict__ Xa,
    const float* __restrict__ W, float* __restrict__ Out) {
  __shared__ __align__(16) unsigned short Asf[128 * 64];
  __shared__ __align__(16) unsigned short Bsf[128 * 64];
  const int tid = threadIdx.x;
  const int bx = blockIdx.x, by = blockIdx.y, bz = blockIdx.z;
  const int S = gridDim.z;
  const int bt0 = bx << 7, o0 = by << 7;
  const int q = 258 / S, r = 258 % S;
  const int c0 = bz * q + (bz < r ? bz : r);
  const int ccnt = q + (bz < r ? 1 : 0);
  const int nK = ccnt << 2;
  const int wid = tid >> 6, lane = tid & 63;
  const int wr = (wid >> 1) << 6, wc = (wid & 1) << 6;
  const int ar = tid >> 1;
  const int ah = (tid & 1) << 5;
  const float* xrow = X + (size_t)(bt0 + ar) * 256;
  const float* varow = Xa + (size_t)(bt0 + ar) * 256;
  f32x4 acc[4][4] = {};
  for (int kt = 0; kt < nK; ++kt) {
    const int c = c0 + (kt >> 2);
    const int j0 = (kt & 3) << 6;
    __syncthreads();
    {
      const float* vs = (c == 257) ? xrow : varow;
      float s = 1.0f;
      if (c < 256) s = xrow[c];
      const f32x4* vp = (const f32x4*)(vs + j0 + ah);
      f32x4 v[8];
#pragma unroll
      for (int qq = 0; qq < 8; ++qq) v[qq] = vp[qq];
      unsigned short* aw = Asf + ar * 64;
      const int sl0 = ah >> 3, sx = ar & 7;
#pragma unroll
      for (int w = 0; w < 4; ++w) {
        bf16x8 pk;
#pragma unroll
        for (int e = 0; e < 8; ++e)
          pk[e] = (short)f2b(s * v[w * 2 + (e >> 2)][e & 3]);
        *(bf16x8*)(aw + (((sl0 + w) ^ sx) << 3)) = pk;
      }
    }
    {
      const int orow = tid >> 1;
      const int jh = (tid & 1) << 5;
      const float* wrow = W + (size_t)(o0 + orow) * DI;
      float tmp[32];
      if (c < 256) {
        const int bse = (c + 1) * 257 + 1 + j0 + jh;
#pragma unroll
        for (int i = 0; i < 32; ++i) tmp[i] = wrow[bse + i];
      } else if (c == 256) {
        const int bse = 1 + j0 + jh;
#pragma unroll
        for (int i = 0; i < 32; ++i) tmp[i] = wrow[bse + i];
      } else {
#pragma unroll
        for (int i = 0; i < 32; ++i) tmp[i] = wrow[(j0 + jh + i + 1) * 257];
      }
      unsigned short* bw = Bsf + orow * 64;
      const int sl0 = jh >> 3, sx = orow & 7;
#pragma unroll
      for (int w = 0; w < 4; ++w) {
        bf16x8 pk;
#pragma unroll
        for (int e = 0; e < 8; ++e) pk[e] = (short)f2b(tmp[w * 8 + e]);
        *(bf16x8*)(bw + (((sl0 + w) ^ sx) << 3)) = pk;
      }
    }
    __syncthreads();
#pragma unroll
    for (int kk = 0; kk < 2; ++kk) {
      const int kslot = (kk << 2) + (lane >> 4);
      bf16x8 af[4], bfr2[4];
#pragma unroll
      for (int fm = 0; fm < 4; ++fm) {
        const int row = wr + (fm << 4) + (lane & 15);
        af[fm] = *(const bf16x8*)(Asf + row * 64 + ((kslot ^ (row & 7)) << 3));
      }
#pragma unroll
      for (int fn = 0; fn < 4; ++fn) {
        const int row = wc + (fn << 4) + (lane & 15);
        bfr2[fn] = *(const bf16x8*)(Bsf + row * 64 + ((kslot ^ (row & 7)) << 3));
      }
#pragma unroll
      for (int fm = 0; fm < 4; ++fm)
#pragma unroll
        for (int fn = 0; fn < 4; ++fn)
          acc[fm][fn] = __builtin_amdgcn_mfma_f32_16x16x32_bf16(
              af[fm], bfr2[fn], acc[fm][fn], 0, 0, 0);
    }
  }
  const int r0 = (lane >> 4) << 2;
  const int cl = lane & 15;
#pragma unroll
  for (int fm = 0; fm < 4; ++fm) {
    const int row = bt0 + wr + (fm << 4) + r0;
#pragma unroll
    for (int fn = 0; fn < 4; ++fn) {
      const int col = o0 + wc + (fn << 4) + cl;
#pragma unroll
      for (int rr = 0; rr < 4; ++rr)
        atomicAdd(Out + (size_t)(row + rr) * 256 + col, acc[fm][fn][rr]);
    }
  }
}

extern "C" void kernel_launch(void* const* d_in, const int* in_sizes, int n_in,
                              void* d_out, int out_size, void* d_ws, size_t ws_size,
                              hipStream_t stream) {
  const float* X  = (const float*)d_in[0];
  const float* Xa = (const float*)d_in[1];
  const float* W  = (const float*)d_in[2];
  const float* b  = (const float*)d_in[3];
  float* out = (float*)d_out;

  const size_t WBF_SZ = (size_t)258 * 256 * 256 * 2;  // 33,816,576 B
  const size_t XT_SZ  = (size_t)256 * 4096 * 4;       //  4,194,304 B
  const size_t PART1  = (size_t)4096 * 256 * 4;       //  4 MiB per slice

  if (ws_size >= WBF_SZ + XT_SZ + 9 * PART1) {
    unsigned short* Bp = (unsigned short*)d_ws;
    float* Xt = (float*)((char*)d_ws + WBF_SZ);
    float* P  = (float*)((char*)d_ws + WBF_SZ + XT_SZ);
    prep_w<<<dim3(258, 64), 256, 0, stream>>>(W, Bp);
    prep_xt<<<dim3(128, 8), dim3(32, 8), 0, stream>>>(X, Xt);
    gemm_r15<<<dim3(288), 512, 0, stream>>>(X, Xa, Xt, Bp, P);
    reduce_k<<<4096, 256, 0, stream>>>(P, W, b, out, 9);
  } else {
    init_k<<<4096, 256, 0, stream>>>(W, b, out);
    gemm_fb<<<dim3(32, 2, 4), 256, 0, stream>>>(X, Xa, W, out);
  }
}